// Round 17
// baseline (2702.853 us; speedup 1.0000x reference)
//
#include <hip/hip_runtime.h>
#include <cstdint>
#include <cstddef>

#define TOKENS 131072      // B*T = 512*256
#define B_BATCH 512
#define T_SEQ 256
#define C_DIM 512
#define H_HEADS 4
#define HS_DIM 128
#define FF_DIM 2048
#define EPS_RMS 1e-8f
#define SM_SCALE 0.044194173824159216f   // 512^-0.5

typedef short bf16x8 __attribute__((ext_vector_type(8)));
typedef float f32x4 __attribute__((ext_vector_type(4)));
typedef unsigned short ushort_t;

__device__ __forceinline__ ushort_t f2bf(float f) {
    uint32_t u = __builtin_bit_cast(uint32_t, f);
    u += 0x7FFFu + ((u >> 16) & 1u);   // round-to-nearest-even
    return (ushort_t)(u >> 16);
}

__device__ __forceinline__ float bf2f(ushort_t u) {
    return __builtin_bit_cast(float, (uint32_t)u << 16);
}

// tanh-form GELU: validated r7/r10/r11/r13/r15/r16 (absmax 0.03125 unchanged).
__device__ __forceinline__ float gelu_f(float x) {
    float u = 0.7978845608028654f * x + 0.035677408136300125f * (x * x * x);
    float e = __expf(2.0f * u);                 // inf-safe: e=inf -> t=1
    float t = 1.0f - 2.0f / (1.0f + e);         // tanh(u)
    return 0.5f * x * (1.0f + t);
}

// async global->LDS, 16B/lane. Dest must be wave-uniform; HW adds lane*16.
__device__ __forceinline__ void stage8k(ushort_t* lds, const ushort_t* g) {
    __builtin_amdgcn_global_load_lds(
        (const __attribute__((address_space(1))) uint32_t*)g,
        (__attribute__((address_space(3))) uint32_t*)lds,
        16, 0, 0);
}

// ---------------------------------------------------------------------------
// Weight prep: fp32 -> bf16, transposed to N x K row-major
// ---------------------------------------------------------------------------
__global__ void prep_qkv(const float* __restrict__ Wq, const float* __restrict__ Wk,
                         const float* __restrict__ Wv, ushort_t* __restrict__ WqkvT) {
    int idx = blockIdx.x * 256 + threadIdx.x;       // over 1536*512
    if (idx >= 1536 * 512) return;
    int n = idx >> 9;
    int k = idx & 511;
    int h = (n & 511) >> 7;
    int d = n & 127;
    float v;
    size_t s = ((size_t)h * 512 + k) * 128 + d;     // (H,C,HS)
    if (n < 512)       v = Wq[s];
    else if (n < 1024) v = Wk[s];
    else               v = Wv[s];
    WqkvT[idx] = f2bf(v);
}

__global__ void prep_bias(const float* __restrict__ bk, float* __restrict__ bias1536) {
    int n = blockIdx.x * 256 + threadIdx.x;
    if (n >= 1536) return;
    bias1536[n] = (n >= 512 && n < 1024) ? bk[n - 512] : 0.0f;   // bk flat (H,HS)
}

__global__ void prep_proj(const float* __restrict__ Wproj, ushort_t* __restrict__ WprojT) {
    int idx = blockIdx.x * 256 + threadIdx.x;       // over 512*512
    if (idx >= 512 * 512) return;
    int n = idx >> 9, k = idx & 511;
    WprojT[idx] = f2bf(Wproj[(size_t)k * 512 + n]);
}

__global__ void prep_wi(const float* __restrict__ Wi, ushort_t* __restrict__ WiT) {
    int idx = blockIdx.x * 256 + threadIdx.x;       // over 2*2048*512
    if (idx >= 2 * 2048 * 512) return;
    int b = idx >> 20;
    int rem = idx & 1048575;
    int f = rem >> 9, c = rem & 511;                // WiT[b*2048+f][c] = [4096][512]
    WiT[idx] = f2bf(Wi[((size_t)b * 512 + c) * 2048 + f]);
}

// WoT2[c][br*2048+f] = 0.5 * Wo[br][f][c]  -> [512][4096] row-major over K=4096
__global__ void prep_wo(const float* __restrict__ Wo, ushort_t* __restrict__ WoT2) {
    int idx = blockIdx.x * 256 + threadIdx.x;       // over 512*4096
    if (idx >= 512 * 4096) return;
    int c  = idx >> 12;
    int n2 = idx & 4095;
    int br = n2 >> 11;
    int f  = n2 & 2047;
    WoT2[idx] = f2bf(0.5f * Wo[(((size_t)br * 2048 + f) * 512) + c]);
}

// ---------------------------------------------------------------------------
// RMSNorm (first norm only): one wave per token, f32 in -> bf16 out.
// ---------------------------------------------------------------------------
__global__ __launch_bounds__(256) void rmsnorm_kernel(const float* __restrict__ in,
                                                      const float* __restrict__ wptr,
                                                      ushort_t* __restrict__ outb) {
    const int lane = threadIdx.x & 63;
    const int wave = threadIdx.x >> 6;
    const size_t token = (size_t)blockIdx.x * 4 + wave;
    const float* row = in + token * 512;
    float4 v0 = *(const float4*)(row + lane * 8);
    float4 v1 = *(const float4*)(row + lane * 8 + 4);
    float ss = v0.x*v0.x + v0.y*v0.y + v0.z*v0.z + v0.w*v0.w
             + v1.x*v1.x + v1.y*v1.y + v1.z*v1.z + v1.w*v1.w;
    #pragma unroll
    for (int d = 32; d; d >>= 1) ss += __shfl_xor(ss, d);
    float scale = wptr[0] * rsqrtf(ss * (1.0f / 512.0f) + EPS_RMS);
    float vals[8] = {v0.x, v0.y, v0.z, v0.w, v1.x, v1.y, v1.z, v1.w};
    union { ushort_t us[8]; uint4 u4; } pk;
    #pragma unroll
    for (int i = 0; i < 8; i++) pk.us[i] = f2bf(vals[i] * scale);
    *(uint4*)(outb + token * 512 + lane * 8) = pk.u4;
}

// ---------------------------------------------------------------------------
// Row-scale kernel: s[m] = w2 * rsqrt(mean(zb[m]^2) + eps); applied in the
// FFN GEMM epilogues via linearity ((s*z)@W = s*(z@W)).  (r15, validated)
// ---------------------------------------------------------------------------
__global__ __launch_bounds__(256) void rowscale_kernel(const ushort_t* __restrict__ zb,
                                                       const float* __restrict__ wptr,
                                                       float* __restrict__ s) {
    const int lane = threadIdx.x & 63;
    const int wave = threadIdx.x >> 6;
    const size_t token = (size_t)blockIdx.x * 4 + wave;
    bf16x8 v = *(const bf16x8*)(zb + token * 512 + lane * 8);
    float ss = 0.0f;
    #pragma unroll
    for (int i = 0; i < 8; i++) { float f = bf2f((ushort_t)v[i]); ss += f * f; }
    #pragma unroll
    for (int d = 32; d; d >>= 1) ss += __shfl_xor(ss, d);
    if (lane == 0) s[token] = wptr[0] * rsqrtf(ss * (1.0f / 512.0f) + EPS_RMS);
}

// ---------------------------------------------------------------------------
// GEMM 128x128, BK=64, 8-phase FIFO counted-vmcnt(6), 64KB LDS -> 2 blocks/CU.
// r17: geometry-halved clone of the r13 schedule (best measured; 0 conflicts).
// Rationale: per K-tile the single-256²-block kernel spends ~9.6k cyc against
// ~2.5k of MFMA+LDS work — exposed phase-boundary latency with ONE barrier
// group per CU. At 64KB LDS two blocks co-reside: block A's MFMA phases hide
// block B's stage/barrier drains (m114 cross-wave overlap).
// 4 waves (2M x 2N); per-wave C = 64x64 (acc 64 VGPR); 8 MFMA per phase.
// Parts: BOTH operands split by row-bit5 (part p = rows with bit5==p), so
// read-phase <-> part mapping mirrors r13 exactly:
//   P1: LDA(b,0) LDB(b,0,bA) | stage A1(t+1)->~b | lgkm0 MM(0,0,bA) BAR
//   P2: LDB(b,1,bB)          | stage A0(t+2)-> b | lgkm0 MM(0,1,bB) BAR
//   P3: LDA(b,1)             | stage B0(t+2)-> b | lgkm0 MM(1,1,bB) BAR
//   P4:                      | stage B1(t+2)-> b | lgkm0+vmcnt(6) MM(1,0,bA) BAR
// (P5-P8 symmetric on ~b). WAR: each stage lands >=1 barrier after its part's
// last read (A1@P1<-prev P3/P7; A0@P2<-P1; B0@P3<-P1; B1@P4<-P2). RAW: FIFO
// vmcnt(6) keeps exactly 3 next-tile parts in flight -> all 4 current-tile
// parts drained before first read (r13 invariant, re-counted for this clone).
// LDS rows are 128B -> the r6-verified XOR swizzle is conflict-free.
// MODE 0: Cb = bf16(acc + bias[c])              (QK projection)
// MODE 1: Cb = bf16(acc + bias[c] + X[idx])     (proj + residual -> z bf16)
// MODE 2: Cb = bf16(gelu(sc[r] * acc))          (FFN up; rms-scale folded)
// MODE 3: Cf = sc[r] * bf2f(Xb[idx]) + acc      (FFN down; x2 = s*z residual)
// MODE 4: Cb = bf16(acc)                        (V^T GEMM, no bias)
// ---------------------------------------------------------------------------
template<int MODE>
__global__ __launch_bounds__(256) void gemm128d(
    const ushort_t* __restrict__ A, const ushort_t* __restrict__ Bt,
    float* Cf, ushort_t* __restrict__ Cb,
    const float* __restrict__ bias, const float* __restrict__ X,
    const ushort_t* __restrict__ Xb, const float* __restrict__ sc,
    int N, int K)
{
    __shared__ __align__(16) ushort_t S[2][2][128 * 64];   // [buf][0=A,1=B] 64KB
    const int tid  = threadIdx.x;
    const int lane = tid & 63;
    const int wave = tid >> 6;         // 0..3
    const int wm = wave >> 1;          // 0..1
    const int wn = wave & 1;           // 0..1

    // XCD-chunked bijective swizzle (all grids here are multiples of 8)
    const int nwg  = (int)gridDim.x;
    const int orig = (int)blockIdx.x;
    const int wgid = (orig & 7) * (nwg >> 3) + (orig >> 3);
    const int gx   = N >> 7;
    const int bm = (wgid / gx) << 7;
    const int bn = (wgid % gx) << 7;

    const int NT = K >> 6;             // K-tiles of 64 (8 or 64 here, even)

    // pre-swizzled global source column (elements): granule (lane&7)^(lane>>3)
    const int sx = (((lane & 7) ^ (lane >> 3)) << 3);

    // part p = rows with bit5==p; issue i covers rows i*64 + p*32 + wave*8;
    // staged row % 8 == lane>>3 (bases are multiples of 8) -> swizzle valid.
    auto stOP = [&](int dbuf, int op, const ushort_t* G, int gbase, int part, int ts) {
        int tc = ts < NT ? ts : NT - 1;
        #pragma unroll
        for (int i = 0; i < 2; i++) {
            int rbase = i * 64 + part * 32 + wave * 8;
            stage8k(&S[dbuf][op][rbase * 64],
                    G + (size_t)(gbase + rbase + (lane >> 3)) * K + tc * 64 + sx);
        }
    };

    const int r16 = lane & 15;
    const int l7  = lane & 7;
    const int q   = lane >> 4;
    const int ge0 = ((q)     ^ l7) << 3;   // k-slice 0 granule elems
    const int ge1 = ((4 + q) ^ l7) << 3;   // k-slice 1

    f32x4 acc[4][4] = {};
    bf16x8 a[2][2], bA[2][2], bB[2][2];

#define STA(DB, P, TS) stOP(DB, 0, A, bm, P, TS)
#define STB(DB, P, TS) stOP(DB, 1, Bt, bn, P, TS)
#define LDA(BUF, MH) { _Pragma("unroll") for (int mf = 0; mf < 2; mf++) { \
    int R = wm * 64 + (MH) * 32 + mf * 16 + r16; \
    a[mf][0] = *(const bf16x8*)&S[BUF][0][R * 64 + ge0]; \
    a[mf][1] = *(const bf16x8*)&S[BUF][0][R * 64 + ge1]; } }
#define LDB(BUF, NH, breg) { _Pragma("unroll") for (int nf = 0; nf < 2; nf++) { \
    int R = wn * 64 + (NH) * 32 + nf * 16 + r16; \
    breg[nf][0] = *(const bf16x8*)&S[BUF][1][R * 64 + ge0]; \
    breg[nf][1] = *(const bf16x8*)&S[BUF][1][R * 64 + ge1]; } }
#define MM(MH, NH, breg) { __builtin_amdgcn_s_setprio(1); \
    _Pragma("unroll") for (int mf = 0; mf < 2; mf++) \
    _Pragma("unroll") for (int nf = 0; nf < 2; nf++) { \
        f32x4 t0 = __builtin_amdgcn_mfma_f32_16x16x32_bf16(a[mf][0], breg[nf][0], acc[(MH)*2+mf][(NH)*2+nf], 0, 0, 0); \
        acc[(MH)*2+mf][(NH)*2+nf] = __builtin_amdgcn_mfma_f32_16x16x32_bf16(a[mf][1], breg[nf][1], t0, 0, 0, 0); } \
    __builtin_amdgcn_s_setprio(0); }
#define BAR    __builtin_amdgcn_s_barrier()
#define WAITL  { asm volatile("s_waitcnt lgkmcnt(0)" ::: "memory"); __builtin_amdgcn_sched_barrier(0); }
#define WAITLV { asm volatile("s_waitcnt lgkmcnt(0)\n\ts_waitcnt vmcnt(6)" ::: "memory"); __builtin_amdgcn_sched_barrier(0); }

    // prologue: FIFO parts [A0,B0,B1,A1](t0)->buf0, [A0,B0,B1](t1)->buf1
    // = 14 issues; vmcnt(6) drains all of tile0, keeps tile1's 3 parts in flight.
    STA(0, 0, 0); STB(0, 0, 0); STB(0, 1, 0); STA(0, 1, 0);
    STA(1, 0, 1); STB(1, 0, 1); STB(1, 1, 1);
    asm volatile("s_waitcnt vmcnt(6)" ::: "memory");
    __builtin_amdgcn_sched_barrier(0);
    BAR;

    const int NI = NT >> 1;
    for (int I = 0; I < NI; ++I) {
        const int t = 2 * I;
        // ---- K-tile t (buf0); single end-of-phase barriers ----
        LDA(0, 0); LDB(0, 0, bA);  STA(1, 1, t + 1);  WAITL;  MM(0, 0, bA); BAR;  // P1
        LDB(0, 1, bB);             STA(0, 0, t + 2);  WAITL;  MM(0, 1, bB); BAR;  // P2
        LDA(0, 1);                 STB(0, 0, t + 2);  WAITL;  MM(1, 1, bB); BAR;  // P3
                                   STB(0, 1, t + 2);  WAITLV; MM(1, 0, bA); BAR;  // P4
        // ---- K-tile t+1 (buf1) ----
        LDA(1, 0); LDB(1, 0, bA);  STA(0, 1, t + 2);  WAITL;  MM(0, 0, bA); BAR;  // P5
        LDB(1, 1, bB);             STA(1, 0, t + 3);  WAITL;  MM(0, 1, bB); BAR;  // P6
        LDA(1, 1);                 STB(1, 0, t + 3);  WAITL;  MM(1, 1, bB); BAR;  // P7
                                   STB(1, 1, t + 3);  WAITLV; MM(1, 0, bA); BAR;  // P8
    }
#undef STA
#undef STB
#undef LDA
#undef LDB
#undef MM
#undef BAR
#undef WAITL
#undef WAITLV

    #pragma unroll
    for (int mi = 0; mi < 4; mi++) {
        #pragma unroll
        for (int ni = 0; ni < 4; ni++) {
            #pragma unroll
            for (int j = 0; j < 4; j++) {
                int r = bm + wm * 64 + mi * 16 + q * 4 + j;
                int c = bn + wn * 64 + ni * 16 + r16;
                float v = acc[mi][ni][j];
                size_t idx = (size_t)r * N + c;
                if (MODE == 0)      { Cb[idx] = f2bf(v + bias[c]); }
                else if (MODE == 1) { Cb[idx] = f2bf(v + bias[c] + X[idx]); }
                else if (MODE == 2) { Cb[idx] = f2bf(gelu_f(sc[r] * v)); }
                else if (MODE == 3) { Cf[idx] = sc[r] * bf2f(Xb[idx]) + v; }
                else                { Cb[idx] = f2bf(v); }
            }
        }
    }
}

// ---------------------------------------------------------------------------
// Fused causal attention v2 (r16, validated): KVBLK=64, pre-transposed V.
// ---------------------------------------------------------------------------
__global__ __launch_bounds__(256) void attn_kernel(const ushort_t* __restrict__ QK,
                                                   const ushort_t* __restrict__ Vt,
                                                   ushort_t* __restrict__ Ao,
                                                   int McTok) {
    __shared__ __align__(16) ushort_t Ks[64 * 136];    // [key][d], pad 136
    __shared__ __align__(16) ushort_t Vs[128 * 72];    // [d][key], pad 72
    __shared__ __align__(16) ushort_t Ps[4][16 * 72];  // per-wave P, pad 72
    const int tid  = threadIdx.x;
    const int lane = tid & 63;
    const int wave = tid >> 6;
    const int qtile = blockIdx.x;                 // 0..3
    const int bh = blockIdx.y;                    // local_b * 4 + h
    const int b = bh >> 2;
    const int h = bh & 3;
    const int q0 = qtile * 64 + wave * 16;
    const size_t baseTok = (size_t)b * T_SEQ;
    const int r16 = lane & 15;
    const int q4  = lane >> 4;

    bf16x8 qf[4];
    {
        const ushort_t* qrow = QK + (baseTok + q0 + r16) * 1024 + h * 128 + q4 * 8;
        #pragma unroll
        for (int dc = 0; dc < 4; dc++)
            qf[dc] = *(const bf16x8*)(qrow + dc * 32);
    }

    float m_run[4], l_run[4];
    f32x4 o[8];
    #pragma unroll
    for (int j = 0; j < 4; j++) { m_run[j] = -INFINITY; l_run[j] = 0.0f; }
    #pragma unroll
    for (int nt = 0; nt < 8; nt++) o[nt] = f32x4{0.f, 0.f, 0.f, 0.f};

    for (int kc = 0; kc <= qtile; kc++) {
        const int kbase = kc * 64;
        __syncthreads();
        #pragma unroll
        for (int i = 0; i < 4; i++) {
            int g = i * 256 + tid;          // 64 rows x 16 granules
            int row = g >> 4, c16 = g & 15;
            uint4 vk = *(const uint4*)(QK + (baseTok + kbase + row) * 1024
                                       + 512 + h * 128 + c16 * 8);
            *(uint4*)(&Ks[row * 136 + c16 * 8]) = vk;
        }
        #pragma unroll
        for (int i = 0; i < 4; i++) {
            int g = i * 256 + tid;          // 128 rows x 8 granules
            int d = g >> 3, c8 = g & 7;
            uint4 vv = *(const uint4*)(Vt + (size_t)(h * 128 + d) * McTok
                                       + baseTok + kbase + c8 * 8);
            *(uint4*)(&Vs[d * 72 + c8 * 8]) = vv;
        }
        __syncthreads();

        f32x4 s[4];
        #pragma unroll
        for (int kt = 0; kt < 4; kt++) s[kt] = f32x4{0.f, 0.f, 0.f, 0.f};
        #pragma unroll
        for (int kt = 0; kt < 4; kt++)
            #pragma unroll
            for (int dc = 0; dc < 4; dc++) {
                bf16x8 kf = *(const bf16x8*)(&Ks[(kt * 16 + r16) * 136 + dc * 32 + q4 * 8]);
                s[kt] = __builtin_amdgcn_mfma_f32_16x16x32_bf16(qf[dc], kf, s[kt], 0, 0, 0);
            }

        float alpha[4];
        #pragma unroll
        for (int j = 0; j < 4; j++) {
            int qrow = q0 + q4 * 4 + j;
            float sv[4];
            #pragma unroll
            for (int kt = 0; kt < 4; kt++) {
                int key = kbase + kt * 16 + r16;
                sv[kt] = (key <= qrow) ? s[kt][j] * SM_SCALE : -INFINITY;
            }
            float mx = fmaxf(fmaxf(sv[0], sv[1]), fmaxf(sv[2], sv[3]));
            #pragma unroll
            for (int d = 1; d < 16; d <<= 1) mx = fmaxf(mx, __shfl_xor(mx, d));
            float mnew = fmaxf(m_run[j], mx);
            float aa = expf(m_run[j] - mnew);
            float rs = 0.0f;
            int rloc = q4 * 4 + j;
            #pragma unroll
            for (int kt = 0; kt < 4; kt++) {
                float p = expf(sv[kt] - mnew);
                rs += p;
                Ps[wave][rloc * 72 + kt * 16 + r16] = f2bf(p);
            }
            #pragma unroll
            for (int d = 1; d < 16; d <<= 1) rs += __shfl_xor(rs, d);
            l_run[j] = l_run[j] * aa + rs;
            m_run[j] = mnew;
            alpha[j] = aa;
        }
        #pragma unroll
        for (int nt = 0; nt < 8; nt++)
            #pragma unroll
            for (int j = 0; j < 4; j++) o[nt][j] *= alpha[j];

        #pragma unroll
        for (int kg = 0; kg < 2; kg++) {
            bf16x8 pa = *(const bf16x8*)(&Ps[wave][r16 * 72 + kg * 32 + q4 * 8]);
            #pragma unroll
            for (int nt = 0; nt < 8; nt++) {
                bf16x8 vf = *(const bf16x8*)(&Vs[(nt * 16 + r16) * 72 + kg * 32 + q4 * 8]);
                o[nt] = __builtin_amdgcn_mfma_f32_16x16x32_bf16(pa, vf, o[nt], 0, 0, 0);
            }
        }
    }

    #pragma unroll
    for (int j = 0; j < 4; j++) {
        float inv = 1.0f / l_run[j];
        size_t row = baseTok + q0 + q4 * 4 + j;
        #pragma unroll
        for (int nt = 0; nt < 8; nt++)
            Ao[row * 512 + h * 128 + nt * 16 + r16] = f2bf(o[nt][j] * inv);
    }
}

// ---------------------------------------------------------------------------
extern "C" void kernel_launch(void* const* d_in, const int* in_sizes, int n_in,
                              void* d_out, int out_size, void* d_ws, size_t ws_size,
                              hipStream_t stream) {
    const float* x     = (const float*)d_in[0];
    const float* Wq    = (const float*)d_in[1];
    const float* Wk    = (const float*)d_in[2];
    const float* bk    = (const float*)d_in[3];
    const float* Wv    = (const float*)d_in[4];
    const float* Wproj = (const float*)d_in[5];
    const float* bproj = (const float*)d_in[6];
    const float* w1    = (const float*)d_in[7];
    const float* w2    = (const float*)d_in[8];
    const float* Wi    = (const float*)d_in[9];
    const float* Wo    = (const float*)d_in[10];
    float* out = (float*)d_out;
    (void)in_sizes; (void)n_in; (void)out_size;

    char* ws = (char*)d_ws;
    size_t off = 0;
    auto alloc = [&](size_t bytes) -> void* {
        void* p = ws + off;
        off += (bytes + 255) & ~(size_t)255;
        return p;
    };
    // ---- persistent weights ----
    ushort_t* WqkvT    = (ushort_t*)alloc((size_t)1536 * 512 * 2);
    float*    bias1536 = (float*)   alloc((size_t)1536 * 4);
    ushort_t* WprojT   = (ushort_t*)alloc((size_t)512 * 512 * 2);
    ushort_t* WiT      = (ushort_t*)alloc((size_t)4096 * 512 * 2);
    ushort_t* WoT2     = (ushort_t*)alloc((size_t)512 * 4096 * 2);
    const size_t weightBytes = off;

    // ---- chunking ----
    int nchunks = 1;
    while (nchunks < 64) {
        size_t Mc = (size_t)TOKENS / nchunks;
        size_t need = weightBytes + Mc * 512 * 2 + Mc * 4096 * 2
                    + Mc * 512 * 2 + Mc * 512 * 2 + Mc * 4 + 8192;
        if (need <= ws_size) break;
        nchunks *= 2;
    }
    const size_t Mc = (size_t)TOKENS / nchunks;
    const int    nbChunk = B_BATCH / nchunks;

    ushort_t* hb   = (ushort_t*)alloc(Mc * 512 * 2);    // h -> attn out
    ushort_t* big  = (ushort_t*)alloc(Mc * 4096 * 2);   // qk (1024) -> hmid (4096)
    ushort_t* zb   = (ushort_t*)alloc(Mc * 512 * 2);    // z (bf16)
    ushort_t* vt   = (ushort_t*)alloc(Mc * 512 * 2);    // V^T [dh][token]
    float*    srow = (float*)   alloc(Mc * 4);          // per-row x2 scale

    // ---- weight prep ----
    prep_qkv <<<(1536 * 512 + 255) / 256, 256, 0, stream>>>(Wq, Wk, Wv, WqkvT);
    prep_bias<<<6, 256, 0, stream>>>(bk, bias1536);
    prep_proj<<<1024, 256, 0, stream>>>(Wproj, WprojT);
    prep_wi  <<<8192, 256, 0, stream>>>(Wi, WiT);
    prep_wo  <<<8192, 256, 0, stream>>>(Wo, WoT2);

    for (int ck = 0; ck < nchunks; ck++) {
        const size_t t0 = (size_t)ck * Mc;
        const float* xC   = x + t0 * 512;
        float*       oC   = out + t0 * 512;
        const int    Mi   = (int)Mc;
        const int    mt   = Mi / 128;                    // 128-row M-tiles

        // h = rmsnorm(x, w1) -> hb (bf16)
        rmsnorm_kernel<<<Mi / 4, 256, 0, stream>>>(xC, w1, hb);
        // QK = h @ Wqk^T + bias -> big (bf16, width 1024)
        gemm128d<0><<<mt * 8, 256, 0, stream>>>(
            hb, WqkvT, nullptr, big, bias1536, nullptr, nullptr, nullptr, 1024, 512);
        // V^T = Wv^T @ h^T -> vt[dh][token]
        gemm128d<4><<<4 * mt, 256, 0, stream>>>(
            WqkvT + (size_t)1024 * 512, hb, nullptr, vt,
            nullptr, nullptr, nullptr, nullptr, Mi, 512);
        // attention -> hb (bf16, width 512)
        attn_kernel<<<dim3(T_SEQ / 64, nbChunk * H_HEADS), 256, 0, stream>>>(big, vt, hb, Mi);
        // z = x + attn @ Wproj + bproj -> zb (bf16)
        gemm128d<1><<<mt * 4, 256, 0, stream>>>(
            hb, WprojT, nullptr, zb, bproj, xC, nullptr, nullptr, 512, 512);
        // x2 row scale
        rowscale_kernel<<<Mi / 4, 256, 0, stream>>>(zb, w2, srow);
        // hmid = gelu(s_m * (zb @ WiT^T)) -> big
        gemm128d<2><<<mt * 32, 256, 0, stream>>>(
            zb, WiT, nullptr, big, nullptr, nullptr, nullptr, srow, 4096, 512);
        // out = s_m*zb + hmid @ WoT2^T
        gemm128d<3><<<mt * 4, 256, 0, stream>>>(
            big, WoT2, oC, nullptr, nullptr, nullptr, zb, srow, 512, 4096);
    }
}

// Round 18
// 2289.323 us; speedup vs baseline: 1.1806x; 1.1806x over previous
//
#include <hip/hip_runtime.h>
#include <cstdint>
#include <cstddef>

#define TOKENS 131072      // B*T = 512*256
#define B_BATCH 512
#define T_SEQ 256
#define C_DIM 512
#define H_HEADS 4
#define HS_DIM 128
#define FF_DIM 2048
#define EPS_RMS 1e-8f
#define SM_SCALE 0.044194173824159216f   // 512^-0.5

typedef short bf16x8 __attribute__((ext_vector_type(8)));
typedef float f32x4 __attribute__((ext_vector_type(4)));
typedef unsigned short ushort_t;

__device__ __forceinline__ ushort_t f2bf(float f) {
    uint32_t u = __builtin_bit_cast(uint32_t, f);
    u += 0x7FFFu + ((u >> 16) & 1u);   // round-to-nearest-even
    return (ushort_t)(u >> 16);
}

__device__ __forceinline__ float bf2f(ushort_t u) {
    return __builtin_bit_cast(float, (uint32_t)u << 16);
}

// tanh-form GELU: validated r7/r10/r11/r13/r15/r16 (absmax 0.03125 unchanged).
__device__ __forceinline__ float gelu_f(float x) {
    float u = 0.7978845608028654f * x + 0.035677408136300125f * (x * x * x);
    float e = __expf(2.0f * u);                 // inf-safe: e=inf -> t=1
    float t = 1.0f - 2.0f / (1.0f + e);         // tanh(u)
    return 0.5f * x * (1.0f + t);
}

// async global->LDS, 16B/lane. Dest must be wave-uniform; HW adds lane*16.
__device__ __forceinline__ void stage8k(ushort_t* lds, const ushort_t* g) {
    __builtin_amdgcn_global_load_lds(
        (const __attribute__((address_space(1))) uint32_t*)g,
        (__attribute__((address_space(3))) uint32_t*)lds,
        16, 0, 0);
}

// ---------------------------------------------------------------------------
// Weight prep: fp32 -> bf16, transposed to N x K row-major
// ---------------------------------------------------------------------------
__global__ void prep_qkv(const float* __restrict__ Wq, const float* __restrict__ Wk,
                         const float* __restrict__ Wv, ushort_t* __restrict__ WqkvT) {
    int idx = blockIdx.x * 256 + threadIdx.x;       // over 1536*512
    if (idx >= 1536 * 512) return;
    int n = idx >> 9;
    int k = idx & 511;
    int h = (n & 511) >> 7;
    int d = n & 127;
    float v;
    size_t s = ((size_t)h * 512 + k) * 128 + d;     // (H,C,HS)
    if (n < 512)       v = Wq[s];
    else if (n < 1024) v = Wk[s];
    else               v = Wv[s];
    WqkvT[idx] = f2bf(v);
}

__global__ void prep_bias(const float* __restrict__ bk, float* __restrict__ bias1536) {
    int n = blockIdx.x * 256 + threadIdx.x;
    if (n >= 1536) return;
    bias1536[n] = (n >= 512 && n < 1024) ? bk[n - 512] : 0.0f;   // bk flat (H,HS)
}

__global__ void prep_proj(const float* __restrict__ Wproj, ushort_t* __restrict__ WprojT) {
    int idx = blockIdx.x * 256 + threadIdx.x;       // over 512*512
    if (idx >= 512 * 512) return;
    int n = idx >> 9, k = idx & 511;
    WprojT[idx] = f2bf(Wproj[(size_t)k * 512 + n]);
}

__global__ void prep_wi(const float* __restrict__ Wi, ushort_t* __restrict__ WiT) {
    int idx = blockIdx.x * 256 + threadIdx.x;       // over 2*2048*512
    if (idx >= 2 * 2048 * 512) return;
    int b = idx >> 20;
    int rem = idx & 1048575;
    int f = rem >> 9, c = rem & 511;                // WiT[b*2048+f][c] = [4096][512]
    WiT[idx] = f2bf(Wi[((size_t)b * 512 + c) * 2048 + f]);
}

// WoT2[c][br*2048+f] = 0.5 * Wo[br][f][c]  -> [512][4096] row-major over K=4096
__global__ void prep_wo(const float* __restrict__ Wo, ushort_t* __restrict__ WoT2) {
    int idx = blockIdx.x * 256 + threadIdx.x;       // over 512*4096
    if (idx >= 512 * 4096) return;
    int c  = idx >> 12;
    int n2 = idx & 4095;
    int br = n2 >> 11;
    int f  = n2 & 2047;
    WoT2[idx] = f2bf(0.5f * Wo[(((size_t)br * 2048 + f) * 512) + c]);
}

// ---------------------------------------------------------------------------
// RMSNorm (first norm only): one wave per token, f32 in -> bf16 out.
// ---------------------------------------------------------------------------
__global__ __launch_bounds__(256) void rmsnorm_kernel(const float* __restrict__ in,
                                                      const float* __restrict__ wptr,
                                                      ushort_t* __restrict__ outb) {
    const int lane = threadIdx.x & 63;
    const int wave = threadIdx.x >> 6;
    const size_t token = (size_t)blockIdx.x * 4 + wave;
    const float* row = in + token * 512;
    float4 v0 = *(const float4*)(row + lane * 8);
    float4 v1 = *(const float4*)(row + lane * 8 + 4);
    float ss = v0.x*v0.x + v0.y*v0.y + v0.z*v0.z + v0.w*v0.w
             + v1.x*v1.x + v1.y*v1.y + v1.z*v1.z + v1.w*v1.w;
    #pragma unroll
    for (int d = 32; d; d >>= 1) ss += __shfl_xor(ss, d);
    float scale = wptr[0] * rsqrtf(ss * (1.0f / 512.0f) + EPS_RMS);
    float vals[8] = {v0.x, v0.y, v0.z, v0.w, v1.x, v1.y, v1.z, v1.w};
    union { ushort_t us[8]; uint4 u4; } pk;
    #pragma unroll
    for (int i = 0; i < 8; i++) pk.us[i] = f2bf(vals[i] * scale);
    *(uint4*)(outb + token * 512 + lane * 8) = pk.u4;
}

// ---------------------------------------------------------------------------
// Row-scale kernel: s[m] = w2 * rsqrt(mean(zb[m]^2) + eps); applied in the
// FFN GEMM epilogues via linearity ((s*z)@W = s*(z@W)).  (r15, validated)
// ---------------------------------------------------------------------------
__global__ __launch_bounds__(256) void rowscale_kernel(const ushort_t* __restrict__ zb,
                                                       const float* __restrict__ wptr,
                                                       float* __restrict__ s) {
    const int lane = threadIdx.x & 63;
    const int wave = threadIdx.x >> 6;
    const size_t token = (size_t)blockIdx.x * 4 + wave;
    bf16x8 v = *(const bf16x8*)(zb + token * 512 + lane * 8);
    float ss = 0.0f;
    #pragma unroll
    for (int i = 0; i < 8; i++) { float f = bf2f((ushort_t)v[i]); ss += f * f; }
    #pragma unroll
    for (int d = 32; d; d >>= 1) ss += __shfl_xor(ss, d);
    if (lane == 0) s[token] = wptr[0] * rsqrtf(ss * (1.0f / 512.0f) + EPS_RMS);
}

// ---------------------------------------------------------------------------
// GEMM 256x256, BK=64, 8-phase FIFO counted-vmcnt(6), 128KB LDS — the r13/r15
// kernel (best measured, 0 conflicts). Schedule/ledger unchanged (see r13).
// MODE 0: Cb = bf16(acc + bias[c])              (QK projection)
// MODE 1: Cb = bf16(acc + bias[c] + X[idx])     (proj + residual -> z bf16)
// MODE 2: Cb = bf16(gelu(sc[r] * acc))          (FFN up; rms-scale folded)
// MODE 3: Cf = sc[r] * bf2f(Xb[idx]) + acc      (FFN down; x2 = s*z residual)
// MODE 4: Cb = bf16(acc)                        (V^T GEMM, no bias)
// ---------------------------------------------------------------------------
template<int MODE>
__global__ __launch_bounds__(512) void gemm256(
    const ushort_t* __restrict__ A, const ushort_t* __restrict__ Bt,
    float* Cf, ushort_t* __restrict__ Cb,
    const float* __restrict__ bias, const float* __restrict__ X,
    const ushort_t* __restrict__ Xb, const float* __restrict__ sc,
    int N, int K)
{
    __shared__ __align__(16) ushort_t S[2][2][256 * 64];   // [buf][0=A,1=B] 128KB
    const int tid  = threadIdx.x;
    const int lane = tid & 63;
    const int wave = tid >> 6;
    const int wm = wave >> 2;          // 0..1
    const int wn = wave & 3;           // 0..3

    // XCD-chunked bijective swizzle (nwg % 8 == 0 for all our grids)
    const int nwg  = (int)gridDim.x;
    const int orig = (int)blockIdx.x;
    const int wgid = (orig & 7) * (nwg >> 3) + (orig >> 3);
    const int gx   = N >> 8;
    const int bm = (wgid / gx) << 8;
    const int bn = (wgid % gx) << 8;

    const int NT = K >> 6;             // K-tiles of 64 (NT >= 8, even, here)

    // pre-swizzled global source column (elements): granule (lane&7)^(lane>>3)
    const int sx = (((lane & 7) ^ (lane >> 3)) << 3);

    auto stA = [&](int dbuf, int part, int ts) {
        int tc = ts < NT ? ts : NT - 1;
        #pragma unroll
        for (int i = 0; i < 2; i++) {
            int rbase = i * 128 + part * 64 + wave * 8;
            stage8k(&S[dbuf][0][rbase * 64],
                    A + (size_t)(bm + rbase + (lane >> 3)) * K + tc * 64 + sx);
        }
    };
    auto stB = [&](int dbuf, int part, int ts) {
        int tc = ts < NT ? ts : NT - 1;
        #pragma unroll
        for (int i = 0; i < 2; i++) {
            int rbase = i * 128 + (wave >> 2) * 64 + part * 32 + (wave & 3) * 8;
            stage8k(&S[dbuf][1][rbase * 64],
                    Bt + (size_t)(bn + rbase + (lane >> 3)) * K + tc * 64 + sx);
        }
    };

    const int r16 = lane & 15;
    const int l7  = lane & 7;
    const int q   = lane >> 4;
    const int ge0 = ((q)     ^ l7) << 3;   // k-slice 0 granule elems
    const int ge1 = ((4 + q) ^ l7) << 3;   // k-slice 1

    f32x4 acc[8][4] = {};
    bf16x8 a[4][2], bA[2][2], bB[2][2];

#define LDA(BUF, MH) { _Pragma("unroll") for (int mf = 0; mf < 4; mf++) { \
    int R = wm * 128 + (MH) * 64 + mf * 16 + r16; \
    a[mf][0] = *(const bf16x8*)&S[BUF][0][R * 64 + ge0]; \
    a[mf][1] = *(const bf16x8*)&S[BUF][0][R * 64 + ge1]; } }
#define LDB(BUF, NH, breg) { _Pragma("unroll") for (int nf = 0; nf < 2; nf++) { \
    int R = wn * 64 + (NH) * 32 + nf * 16 + r16; \
    breg[nf][0] = *(const bf16x8*)&S[BUF][1][R * 64 + ge0]; \
    breg[nf][1] = *(const bf16x8*)&S[BUF][1][R * 64 + ge1]; } }
#define MM(MH, NH, breg) { __builtin_amdgcn_s_setprio(1); \
    _Pragma("unroll") for (int mf = 0; mf < 4; mf++) \
    _Pragma("unroll") for (int nf = 0; nf < 2; nf++) { \
        f32x4 t0 = __builtin_amdgcn_mfma_f32_16x16x32_bf16(a[mf][0], breg[nf][0], acc[(MH)*4+mf][(NH)*2+nf], 0, 0, 0); \
        acc[(MH)*4+mf][(NH)*2+nf] = __builtin_amdgcn_mfma_f32_16x16x32_bf16(a[mf][1], breg[nf][1], t0, 0, 0, 0); } \
    __builtin_amdgcn_s_setprio(0); }
#define BAR    __builtin_amdgcn_s_barrier()
#define WAITL  { asm volatile("s_waitcnt lgkmcnt(0)" ::: "memory"); __builtin_amdgcn_sched_barrier(0); }
#define WAITLV { asm volatile("s_waitcnt lgkmcnt(0)\n\ts_waitcnt vmcnt(6)" ::: "memory"); __builtin_amdgcn_sched_barrier(0); }

    // prologue: FIFO half-tiles [A0,B0,B1,A1](0) -> buf0, [A0,B0,B1](1) -> buf1
    stA(0, 0, 0); stB(0, 0, 0); stB(0, 1, 0); stA(0, 1, 0);
    stA(1, 0, 1); stB(1, 0, 1); stB(1, 1, 1);
    asm volatile("s_waitcnt vmcnt(6)" ::: "memory");
    __builtin_amdgcn_sched_barrier(0);
    BAR;

    const int NI = NT >> 1;
    for (int I = 0; I < NI; ++I) {
        const int t = 2 * I;
        // ---- K-tile t (buf0); single end-of-phase barriers ----
        LDA(0, 0); LDB(0, 0, bA);  stA(1, 1, t + 1);  WAITL;  MM(0, 0, bA); BAR;  // P1
        LDB(0, 1, bB);             stA(0, 0, t + 2);  WAITL;  MM(0, 1, bB); BAR;  // P2
        LDA(0, 1);                 stB(0, 0, t + 2);  WAITL;  MM(1, 1, bB); BAR;  // P3
                                   stB(0, 1, t + 2);  WAITLV; MM(1, 0, bA); BAR;  // P4
        // ---- K-tile t+1 (buf1) ----
        LDA(1, 0); LDB(1, 0, bA);  stA(0, 1, t + 2);  WAITL;  MM(0, 0, bA); BAR;  // P5
        LDB(1, 1, bB);             stA(1, 0, t + 3);  WAITL;  MM(0, 1, bB); BAR;  // P6
        LDA(1, 1);                 stB(1, 0, t + 3);  WAITL;  MM(1, 1, bB); BAR;  // P7
                                   stB(1, 1, t + 3);  WAITLV; MM(1, 0, bA); BAR;  // P8
    }
#undef LDA
#undef LDB
#undef MM
#undef BAR
#undef WAITL
#undef WAITLV

    #pragma unroll
    for (int mf = 0; mf < 8; mf++) {
        #pragma unroll
        for (int nf = 0; nf < 4; nf++) {
            #pragma unroll
            for (int j = 0; j < 4; j++) {
                int r = bm + wm * 128 + mf * 16 + (lane >> 4) * 4 + j;
                int c = bn + wn * 64 + nf * 16 + r16;
                float v = acc[mf][nf][j];
                size_t idx = (size_t)r * N + c;
                if (MODE == 0)      { Cb[idx] = f2bf(v + bias[c]); }
                else if (MODE == 1) { Cb[idx] = f2bf(v + bias[c] + X[idx]); }
                else if (MODE == 2) { Cb[idx] = f2bf(gelu_f(sc[r] * v)); }
                else if (MODE == 3) { Cf[idx] = sc[r] * bf2f(Xb[idx]) + v; }
                else                { Cb[idx] = f2bf(v); }
            }
        }
    }
}

// ---------------------------------------------------------------------------
// Fused causal attention v2 (r16, validated): KVBLK=64, pre-transposed V.
// ---------------------------------------------------------------------------
__global__ __launch_bounds__(256) void attn_kernel(const ushort_t* __restrict__ QK,
                                                   const ushort_t* __restrict__ Vt,
                                                   ushort_t* __restrict__ Ao,
                                                   int McTok) {
    __shared__ __align__(16) ushort_t Ks[64 * 136];    // [key][d], pad 136
    __shared__ __align__(16) ushort_t Vs[128 * 72];    // [d][key], pad 72
    __shared__ __align__(16) ushort_t Ps[4][16 * 72];  // per-wave P, pad 72
    const int tid  = threadIdx.x;
    const int lane = tid & 63;
    const int wave = tid >> 6;
    const int qtile = blockIdx.x;                 // 0..3
    const int bh = blockIdx.y;                    // local_b * 4 + h
    const int b = bh >> 2;
    const int h = bh & 3;
    const int q0 = qtile * 64 + wave * 16;
    const size_t baseTok = (size_t)b * T_SEQ;
    const int r16 = lane & 15;
    const int q4  = lane >> 4;

    bf16x8 qf[4];
    {
        const ushort_t* qrow = QK + (baseTok + q0 + r16) * 1024 + h * 128 + q4 * 8;
        #pragma unroll
        for (int dc = 0; dc < 4; dc++)
            qf[dc] = *(const bf16x8*)(qrow + dc * 32);
    }

    float m_run[4], l_run[4];
    f32x4 o[8];
    #pragma unroll
    for (int j = 0; j < 4; j++) { m_run[j] = -INFINITY; l_run[j] = 0.0f; }
    #pragma unroll
    for (int nt = 0; nt < 8; nt++) o[nt] = f32x4{0.f, 0.f, 0.f, 0.f};

    for (int kc = 0; kc <= qtile; kc++) {
        const int kbase = kc * 64;
        __syncthreads();
        #pragma unroll
        for (int i = 0; i < 4; i++) {
            int g = i * 256 + tid;          // 64 rows x 16 granules
            int row = g >> 4, c16 = g & 15;
            uint4 vk = *(const uint4*)(QK + (baseTok + kbase + row) * 1024
                                       + 512 + h * 128 + c16 * 8);
            *(uint4*)(&Ks[row * 136 + c16 * 8]) = vk;
        }
        #pragma unroll
        for (int i = 0; i < 4; i++) {
            int g = i * 256 + tid;          // 128 rows x 8 granules
            int d = g >> 3, c8 = g & 7;
            uint4 vv = *(const uint4*)(Vt + (size_t)(h * 128 + d) * McTok
                                       + baseTok + kbase + c8 * 8);
            *(uint4*)(&Vs[d * 72 + c8 * 8]) = vv;
        }
        __syncthreads();

        f32x4 s[4];
        #pragma unroll
        for (int kt = 0; kt < 4; kt++) s[kt] = f32x4{0.f, 0.f, 0.f, 0.f};
        #pragma unroll
        for (int kt = 0; kt < 4; kt++)
            #pragma unroll
            for (int dc = 0; dc < 4; dc++) {
                bf16x8 kf = *(const bf16x8*)(&Ks[(kt * 16 + r16) * 136 + dc * 32 + q4 * 8]);
                s[kt] = __builtin_amdgcn_mfma_f32_16x16x32_bf16(qf[dc], kf, s[kt], 0, 0, 0);
            }

        float alpha[4];
        #pragma unroll
        for (int j = 0; j < 4; j++) {
            int qrow = q0 + q4 * 4 + j;
            float sv[4];
            #pragma unroll
            for (int kt = 0; kt < 4; kt++) {
                int key = kbase + kt * 16 + r16;
                sv[kt] = (key <= qrow) ? s[kt][j] * SM_SCALE : -INFINITY;
            }
            float mx = fmaxf(fmaxf(sv[0], sv[1]), fmaxf(sv[2], sv[3]));
            #pragma unroll
            for (int d = 1; d < 16; d <<= 1) mx = fmaxf(mx, __shfl_xor(mx, d));
            float mnew = fmaxf(m_run[j], mx);
            float aa = expf(m_run[j] - mnew);
            float rs = 0.0f;
            int rloc = q4 * 4 + j;
            #pragma unroll
            for (int kt = 0; kt < 4; kt++) {
                float p = expf(sv[kt] - mnew);
                rs += p;
                Ps[wave][rloc * 72 + kt * 16 + r16] = f2bf(p);
            }
            #pragma unroll
            for (int d = 1; d < 16; d <<= 1) rs += __shfl_xor(rs, d);
            l_run[j] = l_run[j] * aa + rs;
            m_run[j] = mnew;
            alpha[j] = aa;
        }
        #pragma unroll
        for (int nt = 0; nt < 8; nt++)
            #pragma unroll
            for (int j = 0; j < 4; j++) o[nt][j] *= alpha[j];

        #pragma unroll
        for (int kg = 0; kg < 2; kg++) {
            bf16x8 pa = *(const bf16x8*)(&Ps[wave][r16 * 72 + kg * 32 + q4 * 8]);
            #pragma unroll
            for (int nt = 0; nt < 8; nt++) {
                bf16x8 vf = *(const bf16x8*)(&Vs[(nt * 16 + r16) * 72 + kg * 32 + q4 * 8]);
                o[nt] = __builtin_amdgcn_mfma_f32_16x16x32_bf16(pa, vf, o[nt], 0, 0, 0);
            }
        }
    }

    #pragma unroll
    for (int j = 0; j < 4; j++) {
        float inv = 1.0f / l_run[j];
        size_t row = baseTok + q0 + q4 * 4 + j;
        #pragma unroll
        for (int nt = 0; nt < 8; nt++)
            Ao[row * 512 + h * 128 + nt * 16 + r16] = f2bf(o[nt][j] * inv);
    }
}

// ---------------------------------------------------------------------------
extern "C" void kernel_launch(void* const* d_in, const int* in_sizes, int n_in,
                              void* d_out, int out_size, void* d_ws, size_t ws_size,
                              hipStream_t stream) {
    const float* x     = (const float*)d_in[0];
    const float* Wq    = (const float*)d_in[1];
    const float* Wk    = (const float*)d_in[2];
    const float* bk    = (const float*)d_in[3];
    const float* Wv    = (const float*)d_in[4];
    const float* Wproj = (const float*)d_in[5];
    const float* bproj = (const float*)d_in[6];
    const float* w1    = (const float*)d_in[7];
    const float* w2    = (const float*)d_in[8];
    const float* Wi    = (const float*)d_in[9];
    const float* Wo    = (const float*)d_in[10];
    float* out = (float*)d_out;
    (void)in_sizes; (void)n_in; (void)out_size;

    char* ws = (char*)d_ws;
    size_t off = 0;
    auto alloc = [&](size_t bytes) -> void* {
        void* p = ws + off;
        off += (bytes + 255) & ~(size_t)255;
        return p;
    };
    // ---- persistent weights ----
    ushort_t* WqkvT    = (ushort_t*)alloc((size_t)1536 * 512 * 2);
    float*    bias1536 = (float*)   alloc((size_t)1536 * 4);
    ushort_t* WprojT   = (ushort_t*)alloc((size_t)512 * 512 * 2);
    ushort_t* WiT      = (ushort_t*)alloc((size_t)4096 * 512 * 2);
    ushort_t* WoT2     = (ushort_t*)alloc((size_t)512 * 4096 * 2);
    const size_t weightBytes = off;

    // ---- chunking: hb Mc*1024B, big Mc*8192B, zb Mc*1024B, vt Mc*1024B, s 4B
    int nchunks = 1;
    while (nchunks < 64) {
        size_t Mc = (size_t)TOKENS / nchunks;
        size_t need = weightBytes + Mc * 512 * 2 + Mc * 4096 * 2
                    + Mc * 512 * 2 + Mc * 512 * 2 + Mc * 4 + 8192;
        if (need <= ws_size) break;
        nchunks *= 2;
    }
    const size_t Mc = (size_t)TOKENS / nchunks;
    const int    nbChunk = B_BATCH / nchunks;

    ushort_t* hb   = (ushort_t*)alloc(Mc * 512 * 2);    // h -> attn out
    ushort_t* big  = (ushort_t*)alloc(Mc * 4096 * 2);   // qk (1024) -> hmid (4096)
    ushort_t* zb   = (ushort_t*)alloc(Mc * 512 * 2);    // z (bf16)
    ushort_t* vt   = (ushort_t*)alloc(Mc * 512 * 2);    // V^T [dh][token]
    float*    srow = (float*)   alloc(Mc * 4);          // per-row x2 scale

    // ---- weight prep ----
    prep_qkv <<<(1536 * 512 + 255) / 256, 256, 0, stream>>>(Wq, Wk, Wv, WqkvT);
    prep_bias<<<6, 256, 0, stream>>>(bk, bias1536);
    prep_proj<<<1024, 256, 0, stream>>>(Wproj, WprojT);
    prep_wi  <<<8192, 256, 0, stream>>>(Wi, WiT);
    prep_wo  <<<8192, 256, 0, stream>>>(Wo, WoT2);

    for (int ck = 0; ck < nchunks; ck++) {
        const size_t t0 = (size_t)ck * Mc;
        const float* xC   = x + t0 * 512;
        float*       oC   = out + t0 * 512;
        const int    Mi   = (int)Mc;
        const int    mt   = Mi / 256;                    // 256-row M-tiles

        // h = rmsnorm(x, w1) -> hb (bf16)
        rmsnorm_kernel<<<Mi / 4, 256, 0, stream>>>(xC, w1, hb);
        // QK = h @ Wqk^T + bias -> big (bf16, width 1024)
        gemm256<0><<<mt * 4, 512, 0, stream>>>(
            hb, WqkvT, nullptr, big, bias1536, nullptr, nullptr, nullptr, 1024, 512);
        // V^T = Wv^T @ h^T  (swapped operands: A=WvT[512][512], Bt=hb[Mc][512])
        gemm256<4><<<2 * (Mi / 256), 512, 0, stream>>>(
            WqkvT + (size_t)1024 * 512, hb, nullptr, vt,
            nullptr, nullptr, nullptr, nullptr, Mi, 512);
        // attention -> hb (bf16, width 512)
        attn_kernel<<<dim3(T_SEQ / 64, nbChunk * H_HEADS), 256, 0, stream>>>(big, vt, hb, Mi);
        // z = x + attn @ Wproj + bproj -> zb (bf16)
        gemm256<1><<<mt * 2, 512, 0, stream>>>(
            hb, WprojT, nullptr, zb, bproj, xC, nullptr, nullptr, 512, 512);
        // x2 row scale
        rowscale_kernel<<<Mi / 4, 256, 0, stream>>>(zb, w2, srow);
        // hmid = gelu(s_m * (zb @ WiT^T)) -> big
        gemm256<2><<<mt * 16, 512, 0, stream>>>(
            zb, WiT, nullptr, big, nullptr, nullptr, nullptr, srow, 4096, 512);
        // out = s_m*zb + hmid @ WoT2^T
        gemm256<3><<<mt * 2, 512, 0, stream>>>(
            big, WoT2, oC, nullptr, nullptr, nullptr, zb, srow, 512, 4096);
    }
}